// Round 6
// baseline (716.927 us; speedup 1.0000x reference)
//
#include <hip/hip_runtime.h>

#define N_NODES 50000
#define N_EDGES 800000
#define IN_CH   151
#define HID     128
#define OUT_CH  51
#define EDIM    51
#define WP      64              // padded minor dim for Wc / Mc / w
#define L0STR   34              // LDS staging row stride (floats): 32 rows + 2 pad
#define NBLK    ((N_NODES + 255) / 256)   // 196 scan blocks

static __device__ __forceinline__ unsigned int f2bf(float f) {
    union { float f; unsigned int u; } v; v.f = f;
    unsigned int r = v.u + 0x7FFF + ((v.u >> 16) & 1);
    return r >> 16;
}
static __device__ __forceinline__ float bflo(unsigned int u) {
    return __uint_as_float(u << 16);
}
static __device__ __forceinline__ float bfhi(unsigned int u) {
    return __uint_as_float(u & 0xFFFF0000u);
}

// ---------- small weight-product kernels ----------
__global__ void kw1(const float* __restrict__ We0, const float* __restrict__ W0,
                    const float* __restrict__ be0, const float* __restrict__ W1,
                    const float* __restrict__ Wout,
                    float* __restrict__ M0, float* __restrict__ c0, float* __restrict__ Wc) {
    int t = blockIdx.x * blockDim.x + threadIdx.x;
    if (t < 51 * 128) {
        int i = t / 128, j = t % 128;
        float a = 0.f;
        for (int k = 0; k < IN_CH; ++k) a += We0[i * IN_CH + k] * W0[k * HID + j];
        M0[t] = a;
    } else if (t < 51 * 128 + 128) {
        int j = t - 51 * 128;
        float a = 0.f;
        for (int k = 0; k < IN_CH; ++k) a += be0[k] * W0[k * HID + j];
        c0[j] = a;
    } else if (t < 51 * 128 + 128 + 128 * WP) {
        int u = t - (51 * 128 + 128);
        int i = u / WP, j = u % WP;
        float a = 0.f;
        if (j < OUT_CH)
            for (int k = 0; k < HID; ++k) a += W1[i * HID + k] * Wout[k * OUT_CH + j];
        Wc[i * WP + j] = a;
    }
}

__global__ void kw2(const float* __restrict__ We1, const float* __restrict__ be1,
                    const float* __restrict__ b1, const float* __restrict__ Wout,
                    const float* __restrict__ bout, const float* __restrict__ Wc,
                    float* __restrict__ Mc, float* __restrict__ cc, float* __restrict__ dd) {
    int t = blockIdx.x * blockDim.x + threadIdx.x;
    if (t < 51 * WP) {
        int i = t / WP, j = t % WP;
        float a = 0.f;
        if (j < OUT_CH)
            for (int k = 0; k < HID; ++k) a += We1[i * HID + k] * Wc[k * WP + j];
        Mc[t] = a;
    } else if (t < 51 * WP + 51) {
        int j = t - 51 * WP;
        float a = 0.f;
        for (int k = 0; k < HID; ++k) a += be1[k] * Wc[k * WP + j];
        cc[j] = a;
    } else if (t < 51 * WP + 102) {
        int j = t - (51 * WP + 51);
        float a = 0.f;
        for (int k = 0; k < HID; ++k) a += b1[k] * Wout[k * OUT_CH + j];
        dd[j] = a + bout[j];
    }
}

// ---------- CSR build ----------
__global__ void k_hist(const int* __restrict__ ei, int* __restrict__ deg) {
    int e = blockIdx.x * 256 + threadIdx.x;
    if (e >= N_EDGES) return;
    atomicAdd(&deg[ei[N_EDGES + e]], 1);
}

__global__ void scan1(const int* __restrict__ deg, int* __restrict__ blksum) {
    __shared__ int lds[256];
    int i = blockIdx.x * 256 + threadIdx.x;
    lds[threadIdx.x] = (i < N_NODES) ? deg[i] : 0;
    __syncthreads();
    for (int s = 128; s > 0; s >>= 1) {
        if (threadIdx.x < s) lds[threadIdx.x] += lds[threadIdx.x + s];
        __syncthreads();
    }
    if (threadIdx.x == 0) blksum[blockIdx.x] = lds[0];
}

__global__ void scan2(const int* __restrict__ blksum, int* __restrict__ blkoff) {
    __shared__ int lds[256];
    int v = (threadIdx.x < NBLK) ? blksum[threadIdx.x] : 0;
    lds[threadIdx.x] = v;
    __syncthreads();
    for (int s = 1; s < 256; s <<= 1) {
        int t = (threadIdx.x >= s) ? lds[threadIdx.x - s] : 0;
        __syncthreads();
        lds[threadIdx.x] += t;
        __syncthreads();
    }
    if (threadIdx.x < NBLK) blkoff[threadIdx.x] = lds[threadIdx.x] - v;  // exclusive
}

__global__ void scan3(const int* __restrict__ deg, const int* __restrict__ blkoff,
                      int* __restrict__ row_start, int* __restrict__ cursor) {
    __shared__ int lds[256];
    int i = blockIdx.x * 256 + threadIdx.x;
    int v = (i < N_NODES) ? deg[i] : 0;
    lds[threadIdx.x] = v;
    __syncthreads();
    for (int s = 1; s < 256; s <<= 1) {
        int t = (threadIdx.x >= s) ? lds[threadIdx.x - s] : 0;
        __syncthreads();
        lds[threadIdx.x] += t;
        __syncthreads();
    }
    if (i < N_NODES) {
        int ex = blkoff[blockIdx.x] + lds[threadIdx.x] - v;
        row_start[i] = ex;
        cursor[i] = ex;
    }
    if (blockIdx.x == 0 && threadIdx.x == 0) row_start[N_NODES] = N_EDGES;
}

// writes (eid, src) as one int2 — halves scattered-store line touches
__global__ void k_fill(const int* __restrict__ ei, int* __restrict__ cursor,
                       int2* __restrict__ es) {
    int e = blockIdx.x * 256 + threadIdx.x;
    if (e >= N_EDGES) return;
    int src = ei[e], dst = ei[N_EDGES + e];
    int pos = atomicAdd(&cursor[dst], 1);
    es[pos] = make_int2(e, src);
}

// ---------- wave-paired gather aggregations ----------
// Two waves per node, each handling alternating 64-edge chunks; LDS combine.

// S[n] = sum_{e: dst=n} edge_attr[e]
__global__ void k_agg_S(const float* __restrict__ ea, const int2* __restrict__ es,
                        const int* __restrict__ row_start, float* __restrict__ S) {
    __shared__ float cmb[2][2][64];
    int tid = threadIdx.x;
    int wv = tid >> 6, lane = tid & 63;
    int pair = wv >> 1, h = wv & 1;
    int n = blockIdx.x * 2 + pair;
    bool valid = n < N_NODES;
    int n0 = 0, n1 = 0;
    if (valid) { n0 = row_start[n]; n1 = row_start[n + 1]; }
    float acc = 0.f;
    bool act = lane < EDIM;
    for (int base = n0 + h * 64; base < n1; base += 128) {
        int cnt = min(64, n1 - base);
        int eid_l = (base + lane < n1) ? es[base + lane].x : 0;
        int t = 0;
        for (; t + 8 <= cnt; t += 8) {
            int e0 = __shfl(eid_l, t),     e1 = __shfl(eid_l, t + 1);
            int e2 = __shfl(eid_l, t + 2), e3 = __shfl(eid_l, t + 3);
            int e4 = __shfl(eid_l, t + 4), e5 = __shfl(eid_l, t + 5);
            int e6 = __shfl(eid_l, t + 6), e7 = __shfl(eid_l, t + 7);
            float v0 = act ? ea[(size_t)e0 * EDIM + lane] : 0.f;
            float v1 = act ? ea[(size_t)e1 * EDIM + lane] : 0.f;
            float v2 = act ? ea[(size_t)e2 * EDIM + lane] : 0.f;
            float v3 = act ? ea[(size_t)e3 * EDIM + lane] : 0.f;
            float v4 = act ? ea[(size_t)e4 * EDIM + lane] : 0.f;
            float v5 = act ? ea[(size_t)e5 * EDIM + lane] : 0.f;
            float v6 = act ? ea[(size_t)e6 * EDIM + lane] : 0.f;
            float v7 = act ? ea[(size_t)e7 * EDIM + lane] : 0.f;
            acc += ((v0 + v1) + (v2 + v3)) + ((v4 + v5) + (v6 + v7));
        }
        for (; t < cnt; ++t) {
            int e0 = __shfl(eid_l, t);
            if (act) acc += ea[(size_t)e0 * EDIM + lane];
        }
    }
    cmb[pair][h][lane] = acc;
    __syncthreads();
    if (h == 0 && valid && act)
        S[(size_t)n * EDIM + lane] = cmb[pair][0][lane] + cmb[pair][1][lane];
}

// hacc[n] += sum_{e: dst=n} y[src[e]]   (y bf16-packed, 2 ch per lane)
__global__ void k_agg_h(const unsigned int* __restrict__ yb, const int2* __restrict__ es,
                        const int* __restrict__ row_start, float* __restrict__ hacc) {
    __shared__ float cmb[2][2][128];
    int tid = threadIdx.x;
    int wv = tid >> 6, lane = tid & 63;
    int pair = wv >> 1, h = wv & 1;
    int n = blockIdx.x * 2 + pair;
    bool valid = n < N_NODES;
    int n0 = 0, n1 = 0;
    if (valid) { n0 = row_start[n]; n1 = row_start[n + 1]; }
    float2 acc = make_float2(0.f, 0.f);
    for (int base = n0 + h * 64; base < n1; base += 128) {
        int cnt = min(64, n1 - base);
        int s_l = (base + lane < n1) ? es[base + lane].y : 0;
        int t = 0;
        for (; t + 8 <= cnt; t += 8) {
            int s0 = __shfl(s_l, t),     s1 = __shfl(s_l, t + 1);
            int s2 = __shfl(s_l, t + 2), s3 = __shfl(s_l, t + 3);
            int s4 = __shfl(s_l, t + 4), s5 = __shfl(s_l, t + 5);
            int s6 = __shfl(s_l, t + 6), s7 = __shfl(s_l, t + 7);
            unsigned int v0 = yb[(size_t)s0 * 64 + lane];
            unsigned int v1 = yb[(size_t)s1 * 64 + lane];
            unsigned int v2 = yb[(size_t)s2 * 64 + lane];
            unsigned int v3 = yb[(size_t)s3 * 64 + lane];
            unsigned int v4 = yb[(size_t)s4 * 64 + lane];
            unsigned int v5 = yb[(size_t)s5 * 64 + lane];
            unsigned int v6 = yb[(size_t)s6 * 64 + lane];
            unsigned int v7 = yb[(size_t)s7 * 64 + lane];
            acc.x += ((bflo(v0) + bflo(v1)) + (bflo(v2) + bflo(v3)))
                   + ((bflo(v4) + bflo(v5)) + (bflo(v6) + bflo(v7)));
            acc.y += ((bfhi(v0) + bfhi(v1)) + (bfhi(v2) + bfhi(v3)))
                   + ((bfhi(v4) + bfhi(v5)) + (bfhi(v6) + bfhi(v7)));
        }
        for (; t < cnt; ++t) {
            int s0 = __shfl(s_l, t);
            unsigned int v0 = yb[(size_t)s0 * 64 + lane];
            acc.x += bflo(v0); acc.y += bfhi(v0);
        }
    }
    cmb[pair][h][lane * 2]     = acc.x;
    cmb[pair][h][lane * 2 + 1] = acc.y;
    __syncthreads();
    if (h == 0 && valid) {
        float2* hp = (float2*)(hacc + (size_t)n * HID) + lane;
        float2 old = *hp;
        old.x += cmb[pair][0][lane * 2]     + cmb[pair][1][lane * 2];
        old.y += cmb[pair][0][lane * 2 + 1] + cmb[pair][1][lane * 2 + 1];
        *hp = old;
    }
}

// out[n] += sum_{e: dst=n} w[src[e]]   (w bf16, padded to 64)
__global__ void k_agg_out(const unsigned short* __restrict__ wb, const int2* __restrict__ es,
                          const int* __restrict__ row_start, float* __restrict__ out) {
    __shared__ float cmb[2][2][64];
    int tid = threadIdx.x;
    int wv = tid >> 6, lane = tid & 63;
    int pair = wv >> 1, h = wv & 1;
    int n = blockIdx.x * 2 + pair;
    bool valid = n < N_NODES;
    int n0 = 0, n1 = 0;
    if (valid) { n0 = row_start[n]; n1 = row_start[n + 1]; }
    float acc = 0.f;
    bool act = lane < OUT_CH;
    for (int base = n0 + h * 64; base < n1; base += 128) {
        int cnt = min(64, n1 - base);
        int s_l = (base + lane < n1) ? es[base + lane].y : 0;
        int t = 0;
        for (; t + 8 <= cnt; t += 8) {
            int s0 = __shfl(s_l, t),     s1 = __shfl(s_l, t + 1);
            int s2 = __shfl(s_l, t + 2), s3 = __shfl(s_l, t + 3);
            int s4 = __shfl(s_l, t + 4), s5 = __shfl(s_l, t + 5);
            int s6 = __shfl(s_l, t + 6), s7 = __shfl(s_l, t + 7);
            unsigned int v0 = act ? wb[(size_t)s0 * WP + lane] : 0u;
            unsigned int v1 = act ? wb[(size_t)s1 * WP + lane] : 0u;
            unsigned int v2 = act ? wb[(size_t)s2 * WP + lane] : 0u;
            unsigned int v3 = act ? wb[(size_t)s3 * WP + lane] : 0u;
            unsigned int v4 = act ? wb[(size_t)s4 * WP + lane] : 0u;
            unsigned int v5 = act ? wb[(size_t)s5 * WP + lane] : 0u;
            unsigned int v6 = act ? wb[(size_t)s6 * WP + lane] : 0u;
            unsigned int v7 = act ? wb[(size_t)s7 * WP + lane] : 0u;
            acc += ((bflo(v0) + bflo(v1)) + (bflo(v2) + bflo(v3)))
                 + ((bflo(v4) + bflo(v5)) + (bflo(v6) + bflo(v7)));
        }
        for (; t < cnt; ++t) {
            int s0 = __shfl(s_l, t);
            if (act) acc += bflo((unsigned int)wb[(size_t)s0 * WP + lane]);
        }
    }
    cmb[pair][h][lane] = acc;
    __syncthreads();
    if (h == 0 && valid && act)
        out[(size_t)n * OUT_CH + lane] += cmb[pair][0][lane] + cmb[pair][1][lane];
}

// ---------- layer-0 tiled GEMM: y(bf16) = x@W0 ; hacc = y + S@M0 + (deg+1)*c0 + b0 ----------
// block = 32 rows x 128 cols (1563 blocks, ~6/CU); thread tile 2 rows x 8 cols; 8.7 KB LDS.
__global__ __launch_bounds__(256) void k_layer0(
        const float* __restrict__ x, const float* __restrict__ W0,
        const float* __restrict__ b0, const float* __restrict__ S,
        const int* __restrict__ deg, const float* __restrict__ M0,
        const float* __restrict__ c0,
        unsigned int* __restrict__ yb, float* __restrict__ hacc) {
    __shared__ float aT[64 * L0STR];   // 8704 B
    int tid = threadIdx.x;
    int r_base = blockIdx.x * 32;
    int cg = tid & 15, rg = tid >> 4;
    int c = cg * 8, r0 = rg * 2;

    float4 a0A = make_float4(0.f, 0.f, 0.f, 0.f), a0B = a0A;  // row r0
    float4 a1A = a0A, a1B = a0A;                               // row r0+1

    // ---- x phases: k = 0..150 in chunks of 64 ----
    for (int p = 0; p < 3; ++p) {
        int koff = p * 64;
        int chunk = min(64, IN_CH - koff);
        __syncthreads();
#pragma unroll
        for (int idx = tid; idx < 32 * 64; idx += 256) {
            int r = idx >> 6, kk = idx & 63;
            int row = r_base + r;
            float v = 0.f;
            if (kk < chunk && row < N_NODES) v = x[(size_t)row * IN_CH + koff + kk];
            aT[kk * L0STR + r] = v;
        }
        __syncthreads();
#pragma unroll 4
        for (int kk = 0; kk < chunk; ++kk) {
            int k = koff + kk;
            float4 w0 = *(const float4*)(W0 + k * HID + c);
            float4 w1 = *(const float4*)(W0 + k * HID + c + 4);
            float2 a = *(const float2*)(&aT[kk * L0STR + r0]);
            a0A.x += a.x * w0.x; a0A.y += a.x * w0.y; a0A.z += a.x * w0.z; a0A.w += a.x * w0.w;
            a0B.x += a.x * w1.x; a0B.y += a.x * w1.y; a0B.z += a.x * w1.z; a0B.w += a.x * w1.w;
            a1A.x += a.y * w0.x; a1A.y += a.y * w0.y; a1A.z += a.y * w0.z; a1A.w += a.y * w0.w;
            a1B.x += a.y * w1.x; a1B.y += a.y * w1.y; a1B.z += a.y * w1.z; a1B.w += a.y * w1.w;
        }
    }

    // ---- store y as bf16 ----
    {
        int row = r_base + r0;
        if (row < N_NODES) {
            uint4 pk;
            pk.x = f2bf(a0A.x) | (f2bf(a0A.y) << 16);
            pk.y = f2bf(a0A.z) | (f2bf(a0A.w) << 16);
            pk.z = f2bf(a0B.x) | (f2bf(a0B.y) << 16);
            pk.w = f2bf(a0B.z) | (f2bf(a0B.w) << 16);
            *(uint4*)(yb + (size_t)row * 64 + (c >> 1)) = pk;
        }
        if (row + 1 < N_NODES) {
            uint4 pk;
            pk.x = f2bf(a1A.x) | (f2bf(a1A.y) << 16);
            pk.y = f2bf(a1A.z) | (f2bf(a1A.w) << 16);
            pk.z = f2bf(a1B.x) | (f2bf(a1B.y) << 16);
            pk.w = f2bf(a1B.z) | (f2bf(a1B.w) << 16);
            *(uint4*)(yb + (size_t)(row + 1) * 64 + (c >> 1)) = pk;
        }
    }

    // ---- S phase: k = 0..50 ----
    __syncthreads();
#pragma unroll
    for (int idx = tid; idx < 32 * 64; idx += 256) {
        int r = idx >> 6, kk = idx & 63;
        int row = r_base + r;
        float v = 0.f;
        if (kk < EDIM && row < N_NODES) v = S[(size_t)row * EDIM + kk];
        aT[kk * L0STR + r] = v;
    }
    __syncthreads();
#pragma unroll 4
    for (int kk = 0; kk < EDIM; ++kk) {
        float4 w0 = *(const float4*)(M0 + kk * HID + c);
        float4 w1 = *(const float4*)(M0 + kk * HID + c + 4);
        float2 a = *(const float2*)(&aT[kk * L0STR + r0]);
        a0A.x += a.x * w0.x; a0A.y += a.x * w0.y; a0A.z += a.x * w0.z; a0A.w += a.x * w0.w;
        a0B.x += a.x * w1.x; a0B.y += a.x * w1.y; a0B.z += a.x * w1.z; a0B.w += a.x * w1.w;
        a1A.x += a.y * w0.x; a1A.y += a.y * w0.y; a1A.z += a.y * w0.z; a1A.w += a.y * w0.w;
        a1B.x += a.y * w1.x; a1B.y += a.y * w1.y; a1B.z += a.y * w1.z; a1B.w += a.y * w1.w;
    }

    // ---- epilogue ----
    float4 cv0 = *(const float4*)(c0 + c);
    float4 cv1 = *(const float4*)(c0 + c + 4);
    float4 bv0 = *(const float4*)(b0 + c);
    float4 bv1 = *(const float4*)(b0 + c + 4);
    {
        int row = r_base + r0;
        if (row < N_NODES) {
            float d1 = (float)(deg[row] + 1);
            float4 vA = a0A, vB = a0B;
            vA.x += d1 * cv0.x + bv0.x; vA.y += d1 * cv0.y + bv0.y;
            vA.z += d1 * cv0.z + bv0.z; vA.w += d1 * cv0.w + bv0.w;
            vB.x += d1 * cv1.x + bv1.x; vB.y += d1 * cv1.y + bv1.y;
            vB.z += d1 * cv1.z + bv1.z; vB.w += d1 * cv1.w + bv1.w;
            *(float4*)(hacc + (size_t)row * HID + c) = vA;
            *(float4*)(hacc + (size_t)row * HID + c + 4) = vB;
        }
        if (row + 1 < N_NODES) {
            float d1 = (float)(deg[row + 1] + 1);
            float4 vA = a1A, vB = a1B;
            vA.x += d1 * cv0.x + bv0.x; vA.y += d1 * cv0.y + bv0.y;
            vA.z += d1 * cv0.z + bv0.z; vA.w += d1 * cv0.w + bv0.w;
            vB.x += d1 * cv1.x + bv1.x; vB.y += d1 * cv1.y + bv1.y;
            vB.z += d1 * cv1.z + bv1.z; vB.w += d1 * cv1.w + bv1.w;
            *(float4*)(hacc + (size_t)(row + 1) * HID + c) = vA;
            *(float4*)(hacc + (size_t)(row + 1) * HID + c + 4) = vB;
        }
    }
}

// ---------- layer-1 tiled GEMM: w(bf16) = hacc@Wc ; out = w + S@Mc + (deg+1)*cc + dd ----------
// block = 32 rows x 64 cols (52 live, 1563 blocks); thread tile 2x4; 8.7 KB LDS.
__global__ __launch_bounds__(256) void k_layer1(
        const float* __restrict__ hacc, const float* __restrict__ Wc,
        const float* __restrict__ S, const int* __restrict__ deg,
        const float* __restrict__ Mc, const float* __restrict__ cc,
        const float* __restrict__ dd,
        unsigned int* __restrict__ wb, float* __restrict__ out) {
    __shared__ float aT[64 * L0STR];
    int tid = threadIdx.x;
    int r_base = blockIdx.x * 32;
    int cg = tid & 15, rg = tid >> 4;
    int c = cg * 4, r0 = rg * 2;

    float4 acc0 = make_float4(0.f, 0.f, 0.f, 0.f), acc1 = acc0;

    // ---- h phases: k = 0..127 in chunks of 64 ----
    for (int p = 0; p < 2; ++p) {
        int koff = p * 64;
        __syncthreads();
#pragma unroll
        for (int idx = tid; idx < 32 * 64; idx += 256) {
            int r = idx >> 6, kk = idx & 63;
            int row = r_base + r;
            aT[kk * L0STR + r] = (row < N_NODES) ? hacc[(size_t)row * HID + koff + kk] : 0.f;
        }
        __syncthreads();
#pragma unroll 4
        for (int kk = 0; kk < 64; ++kk) {
            int k = koff + kk;
            float4 wv = *(const float4*)(Wc + k * WP + c);
            float2 a = *(const float2*)(&aT[kk * L0STR + r0]);
            acc0.x += a.x * wv.x; acc0.y += a.x * wv.y; acc0.z += a.x * wv.z; acc0.w += a.x * wv.w;
            acc1.x += a.y * wv.x; acc1.y += a.y * wv.y; acc1.z += a.y * wv.z; acc1.w += a.y * wv.w;
        }
    }

    // ---- store w as bf16 (padded 64) ----
    {
        int row = r_base + r0;
        if (row < N_NODES) {
            uint2 pk;
            pk.x = f2bf(acc0.x) | (f2bf(acc0.y) << 16);
            pk.y = f2bf(acc0.z) | (f2bf(acc0.w) << 16);
            *(uint2*)(wb + (size_t)row * 32 + (c >> 1)) = pk;
        }
        if (row + 1 < N_NODES) {
            uint2 pk;
            pk.x = f2bf(acc1.x) | (f2bf(acc1.y) << 16);
            pk.y = f2bf(acc1.z) | (f2bf(acc1.w) << 16);
            *(uint2*)(wb + (size_t)(row + 1) * 32 + (c >> 1)) = pk;
        }
    }

    // ---- S phase ----
    __syncthreads();
#pragma unroll
    for (int idx = tid; idx < 32 * 64; idx += 256) {
        int r = idx >> 6, kk = idx & 63;
        int row = r_base + r;
        float v = 0.f;
        if (kk < EDIM && row < N_NODES) v = S[(size_t)row * EDIM + kk];
        aT[kk * L0STR + r] = v;
    }
    __syncthreads();
#pragma unroll 4
    for (int kk = 0; kk < EDIM; ++kk) {
        float4 wv = *(const float4*)(Mc + kk * WP + c);
        float2 a = *(const float2*)(&aT[kk * L0STR + r0]);
        acc0.x += a.x * wv.x; acc0.y += a.x * wv.y; acc0.z += a.x * wv.z; acc0.w += a.x * wv.w;
        acc1.x += a.y * wv.x; acc1.y += a.y * wv.y; acc1.z += a.y * wv.z; acc1.w += a.y * wv.w;
    }

    // ---- epilogue: out = acc + (deg+1)*cc + dd, cols < 51 ----
    if (c < OUT_CH) {
        float cv[4], dv[4];
#pragma unroll
        for (int j = 0; j < 4; ++j) {
            int col = c + j;
            cv[j] = (col < OUT_CH) ? cc[col] : 0.f;
            dv[j] = (col < OUT_CH) ? dd[col] : 0.f;
        }
        int row = r_base + r0;
        if (row < N_NODES) {
            float d1 = (float)(deg[row] + 1);
            const float* ap = (const float*)&acc0;
#pragma unroll
            for (int j = 0; j < 4; ++j) {
                int col = c + j;
                if (col < OUT_CH)
                    out[(size_t)row * OUT_CH + col] = ap[j] + d1 * cv[j] + dv[j];
            }
        }
        if (row + 1 < N_NODES) {
            float d1 = (float)(deg[row + 1] + 1);
            const float* ap = (const float*)&acc1;
#pragma unroll
            for (int j = 0; j < 4; ++j) {
                int col = c + j;
                if (col < OUT_CH)
                    out[(size_t)(row + 1) * OUT_CH + col] = ap[j] + d1 * cv[j] + dv[j];
            }
        }
    }
}

extern "C" void kernel_launch(void* const* d_in, const int* in_sizes, int n_in,
                              void* d_out, int out_size, void* d_ws, size_t ws_size,
                              hipStream_t stream) {
    const float* x    = (const float*)d_in[0];
    const float* ea   = (const float*)d_in[1];
    const float* We0  = (const float*)d_in[2];
    const float* be0  = (const float*)d_in[3];
    const float* W0   = (const float*)d_in[4];
    const float* b0   = (const float*)d_in[5];
    const float* We1  = (const float*)d_in[6];
    const float* be1  = (const float*)d_in[7];
    const float* W1   = (const float*)d_in[8];
    const float* b1   = (const float*)d_in[9];
    const float* Wout = (const float*)d_in[10];
    const float* bout = (const float*)d_in[11];
    const int*   ei   = (const int*)d_in[12];
    float* out = (float*)d_out;

    char* p = (char*)d_ws;
    auto alloc = [&](size_t bytes) {
        char* r = p;
        p += (bytes + 255) & ~(size_t)255;
        return r;
    };
    float* S         = (float*)alloc((size_t)N_NODES * EDIM * 4);    // 10.2 MB
    int*   deg       = (int*)  alloc((size_t)N_NODES * 4);
    int*   row_start = (int*)  alloc((size_t)(N_NODES + 1) * 4);
    int*   cursor    = (int*)  alloc((size_t)N_NODES * 4);
    int*   blksum    = (int*)  alloc((size_t)NBLK * 4);
    int*   blkoff    = (int*)  alloc((size_t)NBLK * 4);
    int2*  es        = (int2*) alloc((size_t)N_EDGES * 8);           // 6.4 MB
    unsigned int* yb = (unsigned int*)alloc((size_t)N_NODES * 64 * 4);  // y bf16: 12.8 MB
    float* hacc      = (float*)alloc((size_t)N_NODES * HID * 4);     // 25.6 MB
    unsigned int* wb = (unsigned int*)alloc((size_t)N_NODES * 32 * 4);  // w bf16: 6.4 MB
    float* M0        = (float*)alloc(51 * 128 * 4);
    float* c0        = (float*)alloc(128 * 4);
    float* Wc        = (float*)alloc(128 * WP * 4);
    float* Mc        = (float*)alloc(51 * WP * 4);
    float* cc        = (float*)alloc(51 * 4);
    float* dd        = (float*)alloc(51 * 4);

    hipMemsetAsync(deg, 0, (size_t)N_NODES * 4, stream);

    kw1<<<(51 * 128 + 128 + 128 * WP + 255) / 256, 256, 0, stream>>>(
        We0, W0, be0, W1, Wout, M0, c0, Wc);
    kw2<<<(51 * WP + 102 + 255) / 256, 256, 0, stream>>>(
        We1, be1, b1, Wout, bout, Wc, Mc, cc, dd);

    // CSR build
    k_hist<<<(N_EDGES + 255) / 256, 256, 0, stream>>>(ei, deg);
    scan1<<<NBLK, 256, 0, stream>>>(deg, blksum);
    scan2<<<1, 256, 0, stream>>>(blksum, blkoff);
    scan3<<<NBLK, 256, 0, stream>>>(deg, blkoff, row_start, cursor);
    k_fill<<<(N_EDGES + 255) / 256, 256, 0, stream>>>(ei, cursor, es);

    // S aggregation (gather, wave-paired)
    k_agg_S<<<(N_NODES + 1) / 2, 256, 0, stream>>>(ea, es, row_start, S);

    // layer 0
    k_layer0<<<(N_NODES + 31) / 32, 256, 0, stream>>>(x, W0, b0, S, deg, M0, c0, yb, hacc);
    k_agg_h<<<(N_NODES + 1) / 2, 256, 0, stream>>>(yb, es, row_start, hacc);

    // layer 1 + output projection
    k_layer1<<<(N_NODES + 31) / 32, 256, 0, stream>>>(hacc, Wc, S, deg, Mc, cc, dd, wb, out);
    k_agg_out<<<(N_NODES + 1) / 2, 256, 0, stream>>>((const unsigned short*)wb, es, row_start, out);
}